// Round 10
// baseline (235.908 us; speedup 1.0000x reference)
//
#include <hip/hip_runtime.h>

// AttnGate: q-projection + RoPE + attention scores + top-k block mask.
// Shapes fixed: B=64, Hq=32, Hk=8, G=4, Dm=128, Dg=128, S=512.
// attention_mask all-true -> identity; not read.
// softmax + scale monotone -> rank on raw scores. Output = int32 0/1 (r3).
// r6 learned: monolithic kernel = 77us, ALL utilization low (VALU 20%, HBM 11%,
// occ 38%) -> latency-bound on serial phases + DS reduce chains. This round:
// 3 kernels, each max-parallel, no cross-lane reduce, f64 in-thread accum.
// ws layout: qdf f32[512*128] @ 0; scf f32[512*512] @ 262144 bytes.

constexpr int Sc = 512;

// ---------------- K0: projection + RoPE -> ws.qdf ----------------
__global__ __launch_bounds__(512) void k0_project(
    const float* __restrict__ q,      // (B,1,32,128)
    const float* __restrict__ wq,     // (8,4,128,128)
    const float* __restrict__ cosv,   // (B,1,128)
    const float* __restrict__ sinv,   // (B,1,128)
    float* __restrict__ qdf_ws)       // (512,128)
{
    __shared__ float  qs[512];
    __shared__ double part[4][128];
    __shared__ double qsum[128];

    const int bid = blockIdx.x;       // (b,h) pair
    const int b = bid >> 3;
    const int h = bid & 7;
    const int t = threadIdx.x;

    qs[t] = q[b * 4096 + h * 512 + t];
    __syncthreads();
    {
        const int o = t & 127;        // output dim (coalesced across lanes)
        const int p = t >> 7;         // quarter of the 512 input dims
        const float* wcol = wq + h * 65536 + p * 16384 + o;
        const float* qq = qs + p * 128;
        double a0 = 0.0, a1 = 0.0, a2 = 0.0, a3 = 0.0;
        #pragma unroll 8
        for (int i = 0; i < 128; i += 4) {
            a0 += (double)qq[i]     * (double)wcol[(size_t)(i)     * 128];
            a1 += (double)qq[i + 1] * (double)wcol[(size_t)(i + 1) * 128];
            a2 += (double)qq[i + 2] * (double)wcol[(size_t)(i + 2) * 128];
            a3 += (double)qq[i + 3] * (double)wcol[(size_t)(i + 3) * 128];
        }
        part[p][o] = (a0 + a1) + (a2 + a3);
    }
    __syncthreads();
    if (t < 128)
        qsum[t] = part[0][t] + part[1][t] + part[2][t] + part[3][t];
    __syncthreads();
    if (t < 128) {
        const double x  = qsum[t];
        const double rh = (t < 64) ? -qsum[t + 64] : qsum[t - 64];
        const double c  = (double)cosv[b * 128 + t];
        const double s  = (double)sinv[b * 128 + t];
        qdf_ws[bid * 128 + t] = (float)(x * c + rh * s);
    }
}

// ---------------- K1: scores -> ws.scf ----------------
// 1024 blocks x 256 threads; block = (bh, half), thread = one full k-row.
// 32 contiguous float4 loads per thread, f64 accumulation in registers,
// q via wave-uniform LDS float4 broadcast. No barriers/DS in the hot loop.
__global__ __launch_bounds__(256, 4) void k1_scores(
    const float* __restrict__ kc,     // (B,512,8,128)
    const float* __restrict__ qdf_ws, // (512,128)
    float* __restrict__ scf_ws)       // (512,512)
{
    __shared__ float4 qls[32];        // this (b,h)'s 128-dim query

    const int bid = blockIdx.x;
    const int bh   = bid >> 1;        // 0..511
    const int half = bid & 1;
    const int b = bh >> 3;
    const int h = bh & 7;
    const int t = threadIdx.x;

    if (t < 32)
        qls[t] = ((const float4*)(qdf_ws + bh * 128))[t];
    __syncthreads();

    const int row = half * 256 + t;   // this thread's k-row
    const float4* krow =
        (const float4*)(kc + (size_t)b * 524288 + (size_t)row * 1024 + h * 128);
    double a0 = 0.0, a1 = 0.0;        // split chains
    #pragma unroll 8
    for (int i = 0; i < 32; ++i) {
        const float4 kv = krow[i];
        const float4 qv = qls[i];     // wave-uniform -> LDS broadcast
        a0 += (double)qv.x * kv.x + (double)qv.z * kv.z;
        a1 += (double)qv.y * kv.y + (double)qv.w * kv.w;
    }
    scf_ws[bh * 512 + row] = (float)(a0 + a1);   // coalesced
}

// ---------------- K2: top-k rank count + mask ----------------
__global__ __launch_bounds__(512) void k2_topk(
    const float* __restrict__ scf_ws, // (512,512)
    const int* __restrict__ budget_p,
    const int* __restrict__ sw_p,
    int* __restrict__ out)            // (B,8,512) int32 0/1
{
    __shared__ float scf[512];
    __shared__ unsigned short pc[8][512];

    const int bid = blockIdx.x;       // (b,h)
    const int t = threadIdx.x;

    scf[t] = scf_ws[bid * 512 + t];
    __syncthreads();

    const int budget = budget_p[0];
    const int sw     = sw_p[0];
    int result;

    if (Sc <= budget) {
        result = 1;
    } else {
        const int swc  = sw > 0 ? sw : 0;
        const int nj   = (Sc - swc) > 0 ? (Sc - swc) : 0;
        const int ksel = budget - sw;
        int total = 0;

        if (ksel > 0 && nj > 0) {
            // Key = ordered f32 bits <<9 | (511-idx): strict u64 '>' reproduces
            // top_k's value-desc, index-asc order exactly (keys unique).
            const int w = t >> 6, l = t & 63;
            unsigned long long ck[8];
            int cnt[8];
            #pragma unroll
            for (int r = 0; r < 8; ++r) {
                const int ci = l + 64 * r;
                unsigned u = __float_as_uint(scf[ci]);
                u = (u & 0x80000000u) ? ~u : (u | 0x80000000u);
                ck[r] = ((unsigned long long)u << 9) |
                        (unsigned long long)(511 - ci);
                cnt[r] = 0;
            }
            const int base = nj >> 3, rem = nj & 7;
            const int j0 = w * base + (w < rem ? w : rem);
            const int j1 = j0 + base + (w < rem ? 1 : 0);
            for (int j = j0; j < j1; ++j) {
                unsigned uj = __float_as_uint(scf[j]);   // broadcast read
                uj = (uj & 0x80000000u) ? ~uj : (uj | 0x80000000u);
                const unsigned long long kj =
                    ((unsigned long long)uj << 9) |
                    (unsigned long long)(511 - j);
                #pragma unroll
                for (int r = 0; r < 8; ++r)
                    cnt[r] += (kj > ck[r]) ? 1 : 0;
            }
            #pragma unroll
            for (int r = 0; r < 8; ++r)
                pc[w][l + 64 * r] = (unsigned short)cnt[r];
            __syncthreads();
            #pragma unroll
            for (int r = 0; r < 8; ++r)
                total += pc[r][t];
        }

        bool selected;
        if (t >= nj) selected = true;                 // sliding window
        else         selected = (ksel > 0) && (total < ksel);
        if (t == Sc - 1) selected = true;             // last pos forced
        result = selected ? 1 : 0;
    }

    out[bid * 512 + t] = result;
}

extern "C" void kernel_launch(void* const* d_in, const int* in_sizes, int n_in,
                              void* d_out, int out_size, void* d_ws, size_t ws_size,
                              hipStream_t stream) {
    const float* q    = (const float*)d_in[0];
    const float* kc   = (const float*)d_in[1];
    const float* wq   = (const float*)d_in[2];
    const float* cosv = (const float*)d_in[3];
    const float* sinv = (const float*)d_in[4];
    // d_in[5] = attention_mask (all-true; not read)
    const int* budget_p = (const int*)d_in[6];
    const int* sw_p     = (const int*)d_in[7];
    int* out = (int*)d_out;

    float* qdf_ws = (float*)d_ws;                         // 512*128 f32
    float* scf_ws = (float*)((char*)d_ws + 512 * 128 * 4); // 512*512 f32

    k0_project<<<dim3(512), dim3(512), 0, stream>>>(q, wq, cosv, sinv, qdf_ws);
    k1_scores <<<dim3(1024), dim3(256), 0, stream>>>(kc, qdf_ws, scf_ws);
    k2_topk   <<<dim3(512), dim3(512), 0, stream>>>(scf_ws, budget_p, sw_p, out);
}

// Round 15
// 234.599 us; speedup vs baseline: 1.0056x; 1.0056x over previous
//
#include <hip/hip_runtime.h>

// AttnGate: q-projection + RoPE + attention scores + top-k block mask.
// Shapes fixed: B=64, Hq=32, Hk=8, G=4, Dm=128, Dg=128, S=512.
// attention_mask all-true -> identity; not read.
// softmax + scale monotone -> rank on raw scores. Output = int32 0/1 (r3).
// History: r6 monolith 77us kernel, HBM 0.9 TB/s during kernel -> the kc
// stream IS the kernel, MLP-starved (needs only ~9KB in flight/CU for peak).
// r10 3-kernel split: graded 235.9 (+12.5 vs monolith) -> split overhead real,
// phase cost unchanged. This round: K1 rebuilt for concurrency — half-row per
// thread, 2048 blocks x 256 thr (8 blk/CU, launch_bounds(256,8)), 16
// independent float4 loads/thread, 4 f64 chains, single shfl_xor combine.
// K0/K2 byte-identical to r10 for clean attribution.
// ws layout: qdf f32[512*128] @ 0; scf f32[512*512] @ 262144 bytes.

constexpr int Sc = 512;

// ---------------- K0: projection + RoPE -> ws.qdf ----------------
__global__ __launch_bounds__(512) void k0_project(
    const float* __restrict__ q,      // (B,1,32,128)
    const float* __restrict__ wq,     // (8,4,128,128)
    const float* __restrict__ cosv,   // (B,1,128)
    const float* __restrict__ sinv,   // (B,1,128)
    float* __restrict__ qdf_ws)       // (512,128)
{
    __shared__ float  qs[512];
    __shared__ double part[4][128];
    __shared__ double qsum[128];

    const int bid = blockIdx.x;       // (b,h) pair
    const int b = bid >> 3;
    const int h = bid & 7;
    const int t = threadIdx.x;

    qs[t] = q[b * 4096 + h * 512 + t];
    __syncthreads();
    {
        const int o = t & 127;        // output dim (coalesced across lanes)
        const int p = t >> 7;         // quarter of the 512 input dims
        const float* wcol = wq + h * 65536 + p * 16384 + o;
        const float* qq = qs + p * 128;
        double a0 = 0.0, a1 = 0.0, a2 = 0.0, a3 = 0.0;
        #pragma unroll 8
        for (int i = 0; i < 128; i += 4) {
            a0 += (double)qq[i]     * (double)wcol[(size_t)(i)     * 128];
            a1 += (double)qq[i + 1] * (double)wcol[(size_t)(i + 1) * 128];
            a2 += (double)qq[i + 2] * (double)wcol[(size_t)(i + 2) * 128];
            a3 += (double)qq[i + 3] * (double)wcol[(size_t)(i + 3) * 128];
        }
        part[p][o] = (a0 + a1) + (a2 + a3);
    }
    __syncthreads();
    if (t < 128)
        qsum[t] = part[0][t] + part[1][t] + part[2][t] + part[3][t];
    __syncthreads();
    if (t < 128) {
        const double x  = qsum[t];
        const double rh = (t < 64) ? -qsum[t + 64] : qsum[t - 64];
        const double c  = (double)cosv[b * 128 + t];
        const double s  = (double)sinv[b * 128 + t];
        qdf_ws[bid * 128 + t] = (float)(x * c + rh * s);
    }
}

// ---------------- K1: scores -> ws.scf (rebuilt for MLP) ----------------
// 2048 blocks x 256 threads; block = (bh, row-quarter); thread = HALF a k-row
// (64 contiguous floats = 16 independent float4 loads). 8 blocks/CU -> up to
// 32 waves/CU (launch_bounds(256,8) caps VGPR at 64). Light VALU per thread
// (64 f64 FMA in 4 chains). One shfl_xor(1) pair-combine outside the loop.
__global__ __launch_bounds__(256, 8) void k1_scores(
    const float* __restrict__ kc,     // (B,512,8,128)
    const float* __restrict__ qdf_ws, // (512,128)
    float* __restrict__ scf_ws)       // (512,512)
{
    __shared__ float4 qls[32];        // this (b,h)'s 128-dim query

    const int bid = blockIdx.x;
    const int bh = bid >> 2;          // 0..511
    const int rq = bid & 3;           // row quarter
    const int t = threadIdx.x;

    if (t < 32)
        qls[t] = ((const float4*)(qdf_ws + bh * 128))[t];
    __syncthreads();

    const int b = bh >> 3;
    const int h = bh & 7;
    const int row  = rq * 128 + (t >> 1);  // this thread-pair's k-row
    const int half = t & 1;                // which 64-float half of the row

    const float4* kp = (const float4*)(kc + (size_t)b * 524288 +
                                       (size_t)row * 1024 + h * 128 + half * 64);
    const float4* qp = qls + half * 16;

    double a0 = 0.0, a1 = 0.0, a2 = 0.0, a3 = 0.0;   // 4 split chains
    #pragma unroll
    for (int i = 0; i < 16; i += 4) {
        const float4 k0 = kp[i],     k1 = kp[i + 1];
        const float4 k2 = kp[i + 2], k3 = kp[i + 3];
        const float4 q0 = qp[i],     q1 = qp[i + 1];
        const float4 q2 = qp[i + 2], q3 = qp[i + 3];
        a0 += (double)q0.x * k0.x + (double)q0.y * k0.y +
              (double)q0.z * k0.z + (double)q0.w * k0.w;
        a1 += (double)q1.x * k1.x + (double)q1.y * k1.y +
              (double)q1.z * k1.z + (double)q1.w * k1.w;
        a2 += (double)q2.x * k2.x + (double)q2.y * k2.y +
              (double)q2.z * k2.z + (double)q2.w * k2.w;
        a3 += (double)q3.x * k3.x + (double)q3.y * k3.y +
              (double)q3.z * k3.z + (double)q3.w * k3.w;
    }
    double acc = (a0 + a1) + (a2 + a3);
    acc += __shfl_xor(acc, 1, 64);    // combine halves (lanes t, t^1)
    if (half == 0)
        scf_ws[bh * 512 + row] = (float)acc;
}

// ---------------- K2: top-k rank count + mask ----------------
__global__ __launch_bounds__(512) void k2_topk(
    const float* __restrict__ scf_ws, // (512,512)
    const int* __restrict__ budget_p,
    const int* __restrict__ sw_p,
    int* __restrict__ out)            // (B,8,512) int32 0/1
{
    __shared__ float scf[512];
    __shared__ unsigned short pc[8][512];

    const int bid = blockIdx.x;       // (b,h)
    const int t = threadIdx.x;

    scf[t] = scf_ws[bid * 512 + t];
    __syncthreads();

    const int budget = budget_p[0];
    const int sw     = sw_p[0];
    int result;

    if (Sc <= budget) {
        result = 1;
    } else {
        const int swc  = sw > 0 ? sw : 0;
        const int nj   = (Sc - swc) > 0 ? (Sc - swc) : 0;
        const int ksel = budget - sw;
        int total = 0;

        if (ksel > 0 && nj > 0) {
            // Key = ordered f32 bits <<9 | (511-idx): strict u64 '>' reproduces
            // top_k's value-desc, index-asc order exactly (keys unique).
            const int w = t >> 6, l = t & 63;
            unsigned long long ck[8];
            int cnt[8];
            #pragma unroll
            for (int r = 0; r < 8; ++r) {
                const int ci = l + 64 * r;
                unsigned u = __float_as_uint(scf[ci]);
                u = (u & 0x80000000u) ? ~u : (u | 0x80000000u);
                ck[r] = ((unsigned long long)u << 9) |
                        (unsigned long long)(511 - ci);
                cnt[r] = 0;
            }
            const int base = nj >> 3, rem = nj & 7;
            const int j0 = w * base + (w < rem ? w : rem);
            const int j1 = j0 + base + (w < rem ? 1 : 0);
            for (int j = j0; j < j1; ++j) {
                unsigned uj = __float_as_uint(scf[j]);   // broadcast read
                uj = (uj & 0x80000000u) ? ~uj : (uj | 0x80000000u);
                const unsigned long long kj =
                    ((unsigned long long)uj << 9) |
                    (unsigned long long)(511 - j);
                #pragma unroll
                for (int r = 0; r < 8; ++r)
                    cnt[r] += (kj > ck[r]) ? 1 : 0;
            }
            #pragma unroll
            for (int r = 0; r < 8; ++r)
                pc[w][l + 64 * r] = (unsigned short)cnt[r];
            __syncthreads();
            #pragma unroll
            for (int r = 0; r < 8; ++r)
                total += pc[r][t];
        }

        bool selected;
        if (t >= nj) selected = true;                 // sliding window
        else         selected = (ksel > 0) && (total < ksel);
        if (t == Sc - 1) selected = true;             // last pos forced
        result = selected ? 1 : 0;
    }

    out[bid * 512 + t] = result;
}

extern "C" void kernel_launch(void* const* d_in, const int* in_sizes, int n_in,
                              void* d_out, int out_size, void* d_ws, size_t ws_size,
                              hipStream_t stream) {
    const float* q    = (const float*)d_in[0];
    const float* kc   = (const float*)d_in[1];
    const float* wq   = (const float*)d_in[2];
    const float* cosv = (const float*)d_in[3];
    const float* sinv = (const float*)d_in[4];
    // d_in[5] = attention_mask (all-true; not read)
    const int* budget_p = (const int*)d_in[6];
    const int* sw_p     = (const int*)d_in[7];
    int* out = (int*)d_out;

    float* qdf_ws = (float*)d_ws;                          // 512*128 f32
    float* scf_ws = (float*)((char*)d_ws + 512 * 128 * 4); // 512*512 f32

    k0_project<<<dim3(512),  dim3(512), 0, stream>>>(q, wq, cosv, sinv, qdf_ws);
    k1_scores <<<dim3(2048), dim3(256), 0, stream>>>(kc, qdf_ws, scf_ws);
    k2_topk   <<<dim3(512),  dim3(512), 0, stream>>>(scf_ws, budget_p, sw_p, out);
}